// Round 7
// baseline (248.185 us; speedup 1.0000x reference)
//
#include <hip/hip_runtime.h>
#include <math.h>

#define N 1024
#define NM1 1023
#define DIM 128
#define LAMB 0.9f
#define INV2SIG2 (1.0f / 450.0f)   // 0.5 / sigma^2, sigma=15

typedef short v8s __attribute__((ext_vector_type(8)));
typedef float v4f __attribute__((ext_vector_type(4)));

__device__ __forceinline__ unsigned short f2bf(float x) {   // RNE float->bf16
    unsigned int u = __float_as_uint(x);
    u += 0x7FFFu + ((u >> 16) & 1u);
    return (unsigned short)(u >> 16);
}
__device__ __forceinline__ float bf2f(unsigned short h) {
    return __uint_as_float(((unsigned int)h) << 16);
}

// ---------------- compose A: S=W3*W2 | R=W1*W4 | t1=W3 b2+b3, t2=W1 b4 | zero-init ---
__global__ __launch_bounds__(256) void k_compose_a(
    const float* __restrict__ w1, const float* __restrict__ w3,
    const float* __restrict__ w2, const float* __restrict__ w4,
    const float* __restrict__ b2, const float* __restrict__ b3,
    const float* __restrict__ b4,
    float* __restrict__ S, float* __restrict__ R,
    float* __restrict__ t1v, float* __restrict__ t2v,
    float* __restrict__ zeros)   // fn2/mag contiguous, 2048 floats
{
    const int b = blockIdx.x;
    const int t = threadIdx.x;
    if (b < 64) {                       // S[i][j] = sum_k W3[i,k] W2[k,j]
        const int i = 2 * b + (t >> 7), j = t & 127;
        float acc = 0.f;
        #pragma unroll 8
        for (int k = 0; k < 128; ++k) acc += w3[i * 128 + k] * w2[k * 128 + j];
        S[i * 128 + j] = acc;
    } else if (b < 128) {               // R[i][j] = sum_k W1[i,k] W4[k,j]
        const int i = 2 * (b - 64) + (t >> 7), j = t & 127;
        float acc = 0.f;
        #pragma unroll 8
        for (int k = 0; k < 128; ++k) acc += w1[i * 128 + k] * w4[k * 128 + j];
        R[i * 128 + j] = acc;
    } else if (b == 128) {
        if (t < 128) {                  // t1 = W3 b2 + b3
            float acc = b3[t];
            #pragma unroll 8
            for (int k = 0; k < 128; ++k) acc += w3[t * 128 + k] * b2[k];
            t1v[t] = acc;
        } else {                        // t2 = W1 b4
            const int i = t - 128;
            float acc = 0.f;
            #pragma unroll 8
            for (int k = 0; k < 128; ++k) acc += w1[i * 128 + k] * b4[k];
            t2v[i] = acc;
        }
    } else {                            // zero fn2/mag
        #pragma unroll
        for (int s = 0; s < 8; ++s) zeros[t + 256 * s] = 0.f;
    }
}

// ---------------- compose B: G=W4*S | X=R*S | bg=W4 t1+b4, bx=R t1+t2+b1 ------------
__global__ __launch_bounds__(256) void k_compose_b(
    const float* __restrict__ w4, const float* __restrict__ S,
    const float* __restrict__ R,
    const float* __restrict__ t1v, const float* __restrict__ t2v,
    const float* __restrict__ b1, const float* __restrict__ b4,
    float* __restrict__ Wboth, float* __restrict__ bboth)
{
    const int b = blockIdx.x;
    const int t = threadIdx.x;
    if (b < 64) {                       // G rows 0-127 of Wboth
        const int i = 2 * b + (t >> 7), j = t & 127;
        float acc = 0.f;
        #pragma unroll 8
        for (int k = 0; k < 128; ++k) acc += w4[i * 128 + k] * S[k * 128 + j];
        Wboth[i * 128 + j] = acc;
    } else if (b < 128) {               // X rows 128-255 of Wboth
        const int i = 2 * (b - 64) + (t >> 7), j = t & 127;
        float acc = 0.f;
        #pragma unroll 8
        for (int k = 0; k < 128; ++k) acc += R[i * 128 + k] * S[k * 128 + j];
        Wboth[(128 + i) * 128 + j] = acc;
    } else {
        if (t < 128) {                  // bg = W4 t1 + b4
            float acc = b4[t];
            #pragma unroll 8
            for (int k = 0; k < 128; ++k) acc += w4[t * 128 + k] * t1v[k];
            bboth[t] = acc;
        } else {                        // bx = R t1 + t2 + b1
            const int i = t - 128;
            float acc = t2v[i] + b1[i];
            #pragma unroll 8
            for (int k = 0; k < 128; ++k) acc += R[i * 128 + k] * t1v[k];
            bboth[128 + i] = acc;
        }
    }
}

// ---------------- K1: Y = f @ Wboth^T + bboth; xb (bf16) + fn2/mag ----------
__global__ __launch_bounds__(256) void k_gemm(
    const float* __restrict__ f, const float* __restrict__ Wb,
    const float* __restrict__ bb,
    unsigned short* __restrict__ xb, float* __restrict__ fn2, float* __restrict__ mag)
{
    __shared__ float4 fl4[64][33];
    __shared__ float4 wl4[64][33];
    __shared__ float bsh[64];
    const int t = threadIdx.x;
    const int row0 = blockIdx.y * 64;
    const int col0 = blockIdx.x * 64;   // over 256 outputs
    const float4* F4 = (const float4*)f;
    const float4* W4p = (const float4*)Wb;

    #pragma unroll
    for (int s = 0; s < 8; ++s) {
        int idx = t + 256 * s;
        int r = idx >> 5, k4 = idx & 31;
        fl4[r][k4] = F4[(row0 + r) * 32 + k4];
        wl4[r][k4] = W4p[(col0 + r) * 32 + k4];
    }
    if (t < 64) bsh[t] = bb[col0 + t];
    __syncthreads();

    const int tx = t & 15, ty = t >> 4;
    float acc[4][4];
    #pragma unroll
    for (int i = 0; i < 4; ++i)
        #pragma unroll
        for (int j = 0; j < 4; ++j) acc[i][j] = 0.f;

    for (int k4 = 0; k4 < 32; ++k4) {
        float4 fa[4], wv[4];
        #pragma unroll
        for (int i = 0; i < 4; ++i) fa[i] = fl4[ty + 16 * i][k4];
        #pragma unroll
        for (int j = 0; j < 4; ++j) wv[j] = wl4[tx + 16 * j][k4];
        #pragma unroll
        for (int i = 0; i < 4; ++i)
            #pragma unroll
            for (int j = 0; j < 4; ++j)
                acc[i][j] += fa[i].x * wv[j].x + fa[i].y * wv[j].y
                           + fa[i].z * wv[j].z + fa[i].w * wv[j].w;
    }

    const bool isg = (col0 < 128);
    #pragma unroll
    for (int i = 0; i < 4; ++i) {
        int gr = row0 + ty + 16 * i;
        float ss = 0.f;
        #pragma unroll
        for (int j = 0; j < 4; ++j) {
            int c = tx + 16 * j;
            float yv = acc[i][j] + bsh[c];
            ss += yv * yv;
            if (!isg) xb[gr * DIM + (col0 - 128) + c] = f2bf(yv);
        }
        #pragma unroll
        for (int off = 1; off < 16; off <<= 1) ss += __shfl_xor(ss, off, 64);
        if (tx == 0) atomicAdd(isg ? &fn2[gr] : &mag[gr], ss);
    }
}

// ---------------- K2: fused affinity + normalize + P0: row-slab, no atomics ---------
__global__ __launch_bounds__(512) void k_affB(
    const unsigned short* __restrict__ xb, const float* __restrict__ mag,
    const float* __restrict__ fn2,
    unsigned short* __restrict__ Bb, unsigned short* __restrict__ BbT,
    float* __restrict__ P0f)
{
    __shared__ float strip[16][1028];
    __shared__ float part[8][16];
    __shared__ float rtot[16];
    const int t = threadIdx.x;
    const int wave = t >> 6, lane = t & 63;
    const int l15 = lane & 15, quad = lane >> 4;
    const int i0 = blockIdx.x * 16;

    const unsigned short* ap = xb + (i0 + l15) * DIM + quad * 8;
    v8s afr[4];
    #pragma unroll
    for (int kc = 0; kc < 4; ++kc) afr[kc] = *(const v8s*)(ap + kc * 32);

    float rowsum[4] = {0.f, 0.f, 0.f, 0.f};
    for (int s = 0; s < 8; ++s) {
        const int j0 = (wave * 8 + s) * 16;
        const unsigned short* bp = xb + (j0 + l15) * DIM + quad * 8;
        v4f acc = {0.f, 0.f, 0.f, 0.f};
        #pragma unroll
        for (int kc = 0; kc < 4; ++kc) {
            v8s b = *(const v8s*)(bp + kc * 32);
            acc = __builtin_amdgcn_mfma_f32_16x16x32_bf16(afr[kc], b, acc, 0, 0, 0);
        }
        const int gj = j0 + l15;
        const float rm = 1.0f / mag[gj];
        const float fj = fn2[gj] * INV2SIG2;
        #pragma unroll
        for (int reg = 0; reg < 4; ++reg) {
            int row = quad * 4 + reg;
            float Sv = acc[reg] * rm - 1.0f;
            float a = ((i0 + row) == gj) ? 0.f : __expf(-(Sv * Sv) * fj);
            strip[row][gj] = a;
            rowsum[reg] += a;
        }
    }
    #pragma unroll
    for (int reg = 0; reg < 4; ++reg) {
        float v = rowsum[reg];
        #pragma unroll
        for (int off = 1; off < 16; off <<= 1) v += __shfl_xor(v, off, 64);
        if (l15 == 0) part[wave][quad * 4 + reg] = v;
    }
    __syncthreads();
    if (t < 16) {
        float s = 0.f;
        #pragma unroll
        for (int w = 0; w < 8; ++w) s += part[w][t];
        rtot[t] = s;
    }
    __syncthreads();

    if (i0 == 0) {
        float r0 = 1.0f / fmaxf(rtot[0], 1e-10f);
        for (int j = t; j < N; j += 512)
            P0f[j] = (j == 0) ? 0.f : strip[0][j] * r0;
    }

    // Bb rows: 2048 8-elem packs, 4 per thread
    #pragma unroll
    for (int it = 0; it < 4; ++it) {
        int pidx = t + 512 * it;
        int row = pidx >> 7;
        int c8 = (pidx & 127) * 8;
        int gi = i0 + row;
        float sc = (gi == 0) ? 0.f : LAMB / fmaxf(rtot[row], 1e-10f);
        float4 v0 = *(const float4*)&strip[row][c8];
        float4 v1 = *(const float4*)&strip[row][c8 + 4];
        uint4 p;
        unsigned short* pp = (unsigned short*)&p;
        pp[0] = f2bf((c8 == 0) ? 0.f : v0.x * sc);
        pp[1] = f2bf(v0.y * sc); pp[2] = f2bf(v0.z * sc); pp[3] = f2bf(v0.w * sc);
        pp[4] = f2bf(v1.x * sc); pp[5] = f2bf(v1.y * sc);
        pp[6] = f2bf(v1.z * sc); pp[7] = f2bf(v1.w * sc);
        *(uint4*)(Bb + gi * N + c8) = p;
    }

    // BbT columns
    #pragma unroll
    for (int it = 0; it < 2; ++it) {
        int j = t + 512 * it;
        uint4 q0, q1;
        unsigned short* qq = (unsigned short*)&q0;
        unsigned short* qq1 = (unsigned short*)&q1;
        #pragma unroll
        for (int r = 0; r < 8; ++r) {
            int gi = i0 + r;
            float sc = (gi == 0 || j == 0) ? 0.f : LAMB / fmaxf(rtot[r], 1e-10f);
            qq[r] = f2bf(strip[r][j] * sc);
        }
        #pragma unroll
        for (int r = 8; r < 16; ++r) {
            float sc = (j == 0) ? 0.f : LAMB / fmaxf(rtot[r], 1e-10f);
            qq1[r - 8] = f2bf(strip[r][j] * sc);
        }
        *(uint4*)(BbT + j * N + i0) = q0;
        *(uint4*)(BbT + j * N + i0 + 8) = q1;
    }
}

// ---------------- K4: generic bf16 MFMA GEMM: C = A*(Bt^T) [+add0 +add1 +diag] ------
// launch_bounds(512,2): grant up to 256 VGPR so the depth-2 prefetch stays in
// registers (default allocator chose 32 VGPR -> no pipelining, 49us).
// koff: per-wave/block K-rotation to spread L2 channel access (2KB row stride
// camps on ~2 channels if all waves start at kc=0). fp32 acc is order-indep.
struct MMArgs {
    const unsigned short* A;
    const unsigned short* Bt;
    const unsigned short* add0;
    const unsigned short* add1;
    int adddiag;
    unsigned short* C;
    unsigned short* CT;
};

__global__ __launch_bounds__(512, 2) void k_mm(MMArgs pa, MMArgs pb)
{
    __shared__ unsigned short Lt[64][65];
    const MMArgs p = (blockIdx.z == 0) ? pa : pb;
    const int t = threadIdx.x;
    const int wave = t >> 6, lane = t & 63;
    const int wm = wave >> 1, wn = wave & 1;
    const int l15 = lane & 15, quad = lane >> 4;
    const int i0 = blockIdx.y * 64, j0 = blockIdx.x * 64;
    const int koff = ((blockIdx.x ^ blockIdx.y) + wave * 4) & 31;

    const unsigned short* ar  = p.A  + (i0 + wm * 16 + l15) * N + quad * 8;
    const unsigned short* b0r = p.Bt + (j0 + wn * 32 + l15) * N + quad * 8;
    const unsigned short* b1r = b0r + 16 * N;

    v4f acc0 = {0.f, 0.f, 0.f, 0.f}, acc1 = {0.f, 0.f, 0.f, 0.f};

    #define KIDX(i) ((((i) + koff) & 31) * 32)
    v8s a0  = *(const v8s*)(ar  + KIDX(0));
    v8s b00 = *(const v8s*)(b0r + KIDX(0));
    v8s b10 = *(const v8s*)(b1r + KIDX(0));
    v8s a1  = *(const v8s*)(ar  + KIDX(1));
    v8s b01 = *(const v8s*)(b0r + KIDX(1));
    v8s b11 = *(const v8s*)(b1r + KIDX(1));

    #pragma unroll
    for (int i = 0; i < 32; i += 2) {
        v8s a2 = a0, b02 = b00, b12 = b10, a3 = a1, b03 = b01, b13 = b11;
        if (i + 2 < 32) {
            a2  = *(const v8s*)(ar  + KIDX(i + 2));
            b02 = *(const v8s*)(b0r + KIDX(i + 2));
            b12 = *(const v8s*)(b1r + KIDX(i + 2));
            a3  = *(const v8s*)(ar  + KIDX(i + 3));
            b03 = *(const v8s*)(b0r + KIDX(i + 3));
            b13 = *(const v8s*)(b1r + KIDX(i + 3));
        }
        acc0 = __builtin_amdgcn_mfma_f32_16x16x32_bf16(a0, b00, acc0, 0, 0, 0);
        acc1 = __builtin_amdgcn_mfma_f32_16x16x32_bf16(a0, b10, acc1, 0, 0, 0);
        acc0 = __builtin_amdgcn_mfma_f32_16x16x32_bf16(a1, b01, acc0, 0, 0, 0);
        acc1 = __builtin_amdgcn_mfma_f32_16x16x32_bf16(a1, b11, acc1, 0, 0, 0);
        a0 = a2; b00 = b02; b10 = b12;
        a1 = a3; b01 = b03; b11 = b13;
    }
    #undef KIDX

    #pragma unroll
    for (int tn = 0; tn < 2; ++tn) {
        int col = wn * 32 + tn * 16 + l15;
        #pragma unroll
        for (int reg = 0; reg < 4; ++reg) {
            int row = wm * 16 + quad * 4 + reg;
            float vv = tn ? acc1[reg] : acc0[reg];
            int gidx = (i0 + row) * N + j0 + col;
            if (p.add0) vv += bf2f(p.add0[gidx]);
            if (p.add1) vv += bf2f(p.add1[gidx]);
            if (p.adddiag && (i0 + row == j0 + col)) vv += 1.0f;
            unsigned short hb = f2bf(vv);
            p.C[gidx] = hb;
            Lt[row][col] = hb;
        }
    }
    if (p.CT) {
        __syncthreads();
        const int c = t >> 3, r0 = (t & 7) * 8;
        uint4 q;
        unsigned short* qq = (unsigned short*)&q;
        #pragma unroll
        for (int e = 0; e < 8; ++e) qq[e] = Lt[r0 + e][c];
        *(uint4*)(p.CT + (j0 + c) * N + i0 + r0) = q;
    }
}

// ---------------- K5: v[r] = base[r] + (M z)[r], bf16 matrix; base may be null ------
__global__ __launch_bounds__(256) void k_mvb(
    const unsigned short* __restrict__ M, const float* __restrict__ base,
    const float* __restrict__ z, float* __restrict__ v)
{
    const int r = (blockIdx.x * 256 + threadIdx.x) >> 6;
    const int lane = threadIdx.x & 63;
    const uint4* m4 = (const uint4*)(M + r * N + lane * 16);
    const float4* z4 = (const float4*)(z + lane * 16);
    uint4 ma = m4[0], mb = m4[1];
    float4 z0 = z4[0], z1 = z4[1], z2 = z4[2], z3 = z4[3];
    float acc = 0.f;
    acc += bf2f((unsigned short)(ma.x)) * z0.x + bf2f((unsigned short)(ma.x >> 16)) * z0.y;
    acc += bf2f((unsigned short)(ma.y)) * z0.z + bf2f((unsigned short)(ma.y >> 16)) * z0.w;
    acc += bf2f((unsigned short)(ma.z)) * z1.x + bf2f((unsigned short)(ma.z >> 16)) * z1.y;
    acc += bf2f((unsigned short)(ma.w)) * z1.z + bf2f((unsigned short)(ma.w >> 16)) * z1.w;
    acc += bf2f((unsigned short)(mb.x)) * z2.x + bf2f((unsigned short)(mb.x >> 16)) * z2.y;
    acc += bf2f((unsigned short)(mb.y)) * z2.z + bf2f((unsigned short)(mb.y >> 16)) * z2.w;
    acc += bf2f((unsigned short)(mb.z)) * z3.x + bf2f((unsigned short)(mb.z >> 16)) * z3.y;
    acc += bf2f((unsigned short)(mb.w)) * z3.z + bf2f((unsigned short)(mb.w >> 16)) * z3.w;
    #pragma unroll
    for (int off = 32; off >= 1; off >>= 1) acc += __shfl_xor(acc, off, 64);
    if (lane == 0) v[r] = (base ? base[r] : 0.f) + acc;
}

// ---------------- K6: epilogue: P=0.1*u; center; relu*100; softmax ----------
__global__ __launch_bounds__(1024) void k_epilogue(const float* __restrict__ uf,
                                                   float* __restrict__ out)
{
    __shared__ float red[16];
    __shared__ float bval;
    const int t = threadIdx.x;
    const int wv = t >> 6, lane = t & 63;
    const bool valid = t < NM1;
    float P = valid ? 0.1f * uf[t + 1] : 0.f;

    float s = P;
    #pragma unroll
    for (int off = 32; off >= 1; off >>= 1) s += __shfl_down(s, off, 64);
    if (lane == 0) red[wv] = s;
    __syncthreads();
    if (t < 64) {
        float s2 = (t < 16) ? red[t] : 0.f;
        #pragma unroll
        for (int off = 8; off >= 1; off >>= 1) s2 += __shfl_down(s2, off, 64);
        if (t == 0) bval = s2 / 1023.0f;
    }
    __syncthreads();
    float mean = bval;
    P = valid ? fmaxf(P - mean, 0.f) * 100.f : 0.f;

    __syncthreads();
    float m = P;
    #pragma unroll
    for (int off = 32; off >= 1; off >>= 1) m = fmaxf(m, __shfl_down(m, off, 64));
    if (lane == 0) red[wv] = m;
    __syncthreads();
    if (t < 64) {
        float m2 = (t < 16) ? red[t] : 0.f;
        #pragma unroll
        for (int off = 8; off >= 1; off >>= 1) m2 = fmaxf(m2, __shfl_down(m2, off, 64));
        if (t == 0) bval = m2;
    }
    __syncthreads();
    float gmax = bval;
    float e = valid ? expf(P - gmax) : 0.f;

    __syncthreads();
    float s3 = e;
    #pragma unroll
    for (int off = 32; off >= 1; off >>= 1) s3 += __shfl_down(s3, off, 64);
    if (lane == 0) red[wv] = s3;
    __syncthreads();
    if (t < 64) {
        float s4 = (t < 16) ? red[t] : 0.f;
        #pragma unroll
        for (int off = 8; off >= 1; off >>= 1) s4 += __shfl_down(s4, off, 64);
        if (t == 0) bval = s4;
    }
    __syncthreads();
    if (valid) out[t] = e / bval;
}

extern "C" void kernel_launch(void* const* d_in, const int* in_sizes, int n_in,
                              void* d_out, int out_size, void* d_ws, size_t ws_size,
                              hipStream_t stream) {
    const float* f  = (const float*)d_in[0];
    const float* w1 = (const float*)d_in[1];
    const float* b1 = (const float*)d_in[2];
    const float* w2 = (const float*)d_in[3];
    const float* b2 = (const float*)d_in[4];
    const float* w3 = (const float*)d_in[5];
    const float* b3 = (const float*)d_in[6];
    const float* w4 = (const float*)d_in[7];
    const float* b4 = (const float*)d_in[8];
    float* ws = (float*)d_ws;

    // Offsets in FLOAT units. bf16 1024x1024 matrix = 524288 floats of space.
    float* S     = ws;                  // 16384
    float* R     = ws + 16384;          // 16384
    float* Wboth = ws + 32768;          // 32768
    float* bboth = ws + 65536;          // 256
    float* t1v   = ws + 65792;          // 128
    float* t2v   = ws + 65920;          // 128
    float* fn2   = ws + 66048;          // 1024 (fn2/mag contiguous for zero-init)
    float* mag   = ws + 67072;          // 1024
    float* P0f   = ws + 68096;          // 1024
    float* t0    = ws + 69120;          // 1024
    float* t1b   = ws + 70144;          // 1024
    unsigned short* xb  = (unsigned short*)(ws + 71168);    // 65536 floats
    unsigned short* Bb  = (unsigned short*)(ws + 136704);   // +524288 floats each
    unsigned short* BbT = (unsigned short*)(ws + 660992);
    unsigned short* B2  = (unsigned short*)(ws + 1185280);
    unsigned short* B2T = (unsigned short*)(ws + 1709568);
    unsigned short* B4  = (unsigned short*)(ws + 2233856);
    unsigned short* B4T = (unsigned short*)(ws + 2758144);
    unsigned short* B8  = (unsigned short*)(ws + 3282432);
    unsigned short* Q2  = (unsigned short*)(ws + 3806720);
    unsigned short* Qm  = (unsigned short*)(ws + 4331008);  // ends 4855296
    float* out = (float*)d_out;

    k_compose_a<<<130, 256, 0, stream>>>(w1, w3, w2, w4, b2, b3, b4,
                                         S, R, t1v, t2v, fn2);
    k_compose_b<<<129, 256, 0, stream>>>(w4, S, R, t1v, t2v, b1, b4, Wboth, bboth);

    k_gemm<<<dim3(4, 16), 256, 0, stream>>>(f, Wboth, bboth, xb, fn2, mag);
    k_affB<<<64, 512, 0, stream>>>(xb, mag, fn2, Bb, BbT, P0f);

    // L6: B2 = B*B (+T)
    MMArgs mm_b2  = {Bb, BbT, nullptr, nullptr, 0, B2, B2T};
    k_mm<<<dim3(16, 16, 1), 512, 0, stream>>>(mm_b2, mm_b2);
    // L7: B4 = B2*B2 (+T)  ||  Q2 = B*B2 + B + B2 + I
    MMArgs mm_b4  = {B2, B2T, nullptr, nullptr, 0, B4, B4T};
    MMArgs mm_q2  = {Bb, B2T, Bb, B2, 1, Q2, nullptr};
    k_mm<<<dim3(16, 16, 2), 512, 0, stream>>>(mm_b4, mm_q2);
    // L8: B8 = B4*B4  ||  Q = Q2*B4 + Q2
    MMArgs mm_b8  = {B4, B4T, nullptr, nullptr, 0, B8, nullptr};
    MMArgs mm_q   = {Q2, B4T, Q2, nullptr, 0, Qm, nullptr};
    k_mm<<<dim3(16, 16, 2), 512, 0, stream>>>(mm_b8, mm_q);

    // bracket: w = sum_{k=0}^{7} (B8)^k P0  (7 applications of w <- P0 + B8 w)
    float* zin = P0f;
    float* zout = t0;
    for (int it = 0; it < 7; ++it) {
        k_mvb<<<256, 256, 0, stream>>>(B8, P0f, zin, zout);
        zin = zout;
        zout = (zin == t0) ? t1b : t0;
    }
    // z = Q * w   (Q = (I+B)(I+B2)(I+B4))
    k_mvb<<<256, 256, 0, stream>>>(Qm, nullptr, zin, zout);

    k_epilogue<<<1, 1024, 0, stream>>>(zout, out);
}

// Round 8
// 139.769 us; speedup vs baseline: 1.7757x; 1.7757x over previous
//
#include <hip/hip_runtime.h>
#include <math.h>

#define N 1024
#define NM1 1023
#define DIM 128
#define LAMB 0.9f
#define INV2SIG2 (1.0f / 450.0f)   // 0.5 / sigma^2, sigma=15
#define MITERS 14                  // Aitken-extrapolated Neumann chain length

typedef short v8s __attribute__((ext_vector_type(8)));
typedef float v4f __attribute__((ext_vector_type(4)));

__device__ __forceinline__ unsigned short f2bf(float x) {   // RNE float->bf16
    unsigned int u = __float_as_uint(x);
    u += 0x7FFFu + ((u >> 16) & 1u);
    return (unsigned short)(u >> 16);
}
__device__ __forceinline__ float bf2f(unsigned short h) {
    return __uint_as_float(((unsigned int)h) << 16);
}

// ---------------- compose A: S=W3*W2 | R=W1*W4 | t1=W3 b2+b3, t2=W1 b4 | zero-init ---
__global__ __launch_bounds__(256) void k_compose_a(
    const float* __restrict__ w1, const float* __restrict__ w3,
    const float* __restrict__ w2, const float* __restrict__ w4,
    const float* __restrict__ b2, const float* __restrict__ b3,
    const float* __restrict__ b4,
    float* __restrict__ S, float* __restrict__ R,
    float* __restrict__ t1v, float* __restrict__ t2v,
    float* __restrict__ zeros)   // fn2/mag contiguous, 2048 floats
{
    const int b = blockIdx.x;
    const int t = threadIdx.x;
    if (b < 64) {                       // S[i][j] = sum_k W3[i,k] W2[k,j]
        const int i = 2 * b + (t >> 7), j = t & 127;
        float acc = 0.f;
        #pragma unroll 8
        for (int k = 0; k < 128; ++k) acc += w3[i * 128 + k] * w2[k * 128 + j];
        S[i * 128 + j] = acc;
    } else if (b < 128) {               // R[i][j] = sum_k W1[i,k] W4[k,j]
        const int i = 2 * (b - 64) + (t >> 7), j = t & 127;
        float acc = 0.f;
        #pragma unroll 8
        for (int k = 0; k < 128; ++k) acc += w1[i * 128 + k] * w4[k * 128 + j];
        R[i * 128 + j] = acc;
    } else if (b == 128) {
        if (t < 128) {                  // t1 = W3 b2 + b3
            float acc = b3[t];
            #pragma unroll 8
            for (int k = 0; k < 128; ++k) acc += w3[t * 128 + k] * b2[k];
            t1v[t] = acc;
        } else {                        // t2 = W1 b4
            const int i = t - 128;
            float acc = 0.f;
            #pragma unroll 8
            for (int k = 0; k < 128; ++k) acc += w1[i * 128 + k] * b4[k];
            t2v[i] = acc;
        }
    } else {                            // zero fn2/mag
        #pragma unroll
        for (int s = 0; s < 8; ++s) zeros[t + 256 * s] = 0.f;
    }
}

// ---------------- compose B: G=W4*S | X=R*S | bg=W4 t1+b4, bx=R t1+t2+b1 ------------
__global__ __launch_bounds__(256) void k_compose_b(
    const float* __restrict__ w4, const float* __restrict__ S,
    const float* __restrict__ R,
    const float* __restrict__ t1v, const float* __restrict__ t2v,
    const float* __restrict__ b1, const float* __restrict__ b4,
    float* __restrict__ Wboth, float* __restrict__ bboth)
{
    const int b = blockIdx.x;
    const int t = threadIdx.x;
    if (b < 64) {                       // G rows 0-127 of Wboth
        const int i = 2 * b + (t >> 7), j = t & 127;
        float acc = 0.f;
        #pragma unroll 8
        for (int k = 0; k < 128; ++k) acc += w4[i * 128 + k] * S[k * 128 + j];
        Wboth[i * 128 + j] = acc;
    } else if (b < 128) {               // X rows 128-255 of Wboth
        const int i = 2 * (b - 64) + (t >> 7), j = t & 127;
        float acc = 0.f;
        #pragma unroll 8
        for (int k = 0; k < 128; ++k) acc += R[i * 128 + k] * S[k * 128 + j];
        Wboth[(128 + i) * 128 + j] = acc;
    } else {
        if (t < 128) {                  // bg = W4 t1 + b4
            float acc = b4[t];
            #pragma unroll 8
            for (int k = 0; k < 128; ++k) acc += w4[t * 128 + k] * t1v[k];
            bboth[t] = acc;
        } else {                        // bx = R t1 + t2 + b1
            const int i = t - 128;
            float acc = t2v[i] + b1[i];
            #pragma unroll 8
            for (int k = 0; k < 128; ++k) acc += R[i * 128 + k] * t1v[k];
            bboth[128 + i] = acc;
        }
    }
}

// ---------------- K1: Y = f @ Wboth^T + bboth; xb (bf16) + fn2/mag ----------
__global__ __launch_bounds__(256) void k_gemm(
    const float* __restrict__ f, const float* __restrict__ Wb,
    const float* __restrict__ bb,
    unsigned short* __restrict__ xb, float* __restrict__ fn2, float* __restrict__ mag)
{
    __shared__ float4 fl4[64][33];
    __shared__ float4 wl4[64][33];
    __shared__ float bsh[64];
    const int t = threadIdx.x;
    const int row0 = blockIdx.y * 64;
    const int col0 = blockIdx.x * 64;   // over 256 outputs
    const float4* F4 = (const float4*)f;
    const float4* W4p = (const float4*)Wb;

    #pragma unroll
    for (int s = 0; s < 8; ++s) {
        int idx = t + 256 * s;
        int r = idx >> 5, k4 = idx & 31;
        fl4[r][k4] = F4[(row0 + r) * 32 + k4];
        wl4[r][k4] = W4p[(col0 + r) * 32 + k4];
    }
    if (t < 64) bsh[t] = bb[col0 + t];
    __syncthreads();

    const int tx = t & 15, ty = t >> 4;
    float acc[4][4];
    #pragma unroll
    for (int i = 0; i < 4; ++i)
        #pragma unroll
        for (int j = 0; j < 4; ++j) acc[i][j] = 0.f;

    for (int k4 = 0; k4 < 32; ++k4) {
        float4 fa[4], wv[4];
        #pragma unroll
        for (int i = 0; i < 4; ++i) fa[i] = fl4[ty + 16 * i][k4];
        #pragma unroll
        for (int j = 0; j < 4; ++j) wv[j] = wl4[tx + 16 * j][k4];
        #pragma unroll
        for (int i = 0; i < 4; ++i)
            #pragma unroll
            for (int j = 0; j < 4; ++j)
                acc[i][j] += fa[i].x * wv[j].x + fa[i].y * wv[j].y
                           + fa[i].z * wv[j].z + fa[i].w * wv[j].w;
    }

    const bool isg = (col0 < 128);
    #pragma unroll
    for (int i = 0; i < 4; ++i) {
        int gr = row0 + ty + 16 * i;
        float ss = 0.f;
        #pragma unroll
        for (int j = 0; j < 4; ++j) {
            int c = tx + 16 * j;
            float yv = acc[i][j] + bsh[c];
            ss += yv * yv;
            if (!isg) xb[gr * DIM + (col0 - 128) + c] = f2bf(yv);
        }
        #pragma unroll
        for (int off = 1; off < 16; off <<= 1) ss += __shfl_xor(ss, off, 64);
        if (tx == 0) atomicAdd(isg ? &fn2[gr] : &mag[gr], ss);
    }
}

// ---------------- K2: fused affinity + normalize + P0: row-slab, no atomics ---------
// Writes Bb only (row-major); no transpose needed anymore (no GEMMs downstream).
__global__ __launch_bounds__(512) void k_affB(
    const unsigned short* __restrict__ xb, const float* __restrict__ mag,
    const float* __restrict__ fn2,
    unsigned short* __restrict__ Bb, float* __restrict__ P0f)
{
    __shared__ float strip[16][1028];
    __shared__ float part[8][16];
    __shared__ float rtot[16];
    const int t = threadIdx.x;
    const int wave = t >> 6, lane = t & 63;
    const int l15 = lane & 15, quad = lane >> 4;
    const int i0 = blockIdx.x * 16;

    const unsigned short* ap = xb + (i0 + l15) * DIM + quad * 8;
    v8s afr[4];
    #pragma unroll
    for (int kc = 0; kc < 4; ++kc) afr[kc] = *(const v8s*)(ap + kc * 32);

    float rowsum[4] = {0.f, 0.f, 0.f, 0.f};
    for (int s = 0; s < 8; ++s) {
        const int j0 = (wave * 8 + s) * 16;
        const unsigned short* bp = xb + (j0 + l15) * DIM + quad * 8;
        v4f acc = {0.f, 0.f, 0.f, 0.f};
        #pragma unroll
        for (int kc = 0; kc < 4; ++kc) {
            v8s b = *(const v8s*)(bp + kc * 32);
            acc = __builtin_amdgcn_mfma_f32_16x16x32_bf16(afr[kc], b, acc, 0, 0, 0);
        }
        const int gj = j0 + l15;
        const float rm = 1.0f / mag[gj];
        const float fj = fn2[gj] * INV2SIG2;
        #pragma unroll
        for (int reg = 0; reg < 4; ++reg) {
            int row = quad * 4 + reg;
            float Sv = acc[reg] * rm - 1.0f;
            float a = ((i0 + row) == gj) ? 0.f : __expf(-(Sv * Sv) * fj);
            strip[row][gj] = a;
            rowsum[reg] += a;
        }
    }
    #pragma unroll
    for (int reg = 0; reg < 4; ++reg) {
        float v = rowsum[reg];
        #pragma unroll
        for (int off = 1; off < 16; off <<= 1) v += __shfl_xor(v, off, 64);
        if (l15 == 0) part[wave][quad * 4 + reg] = v;
    }
    __syncthreads();
    if (t < 16) {
        float s = 0.f;
        #pragma unroll
        for (int w = 0; w < 8; ++w) s += part[w][t];
        rtot[t] = s;
    }
    __syncthreads();

    if (i0 == 0) {
        float r0 = 1.0f / fmaxf(rtot[0], 1e-10f);
        for (int j = t; j < N; j += 512)
            P0f[j] = (j == 0) ? 0.f : strip[0][j] * r0;
    }

    // Bb rows: 2048 8-elem packs, 4 per thread
    #pragma unroll
    for (int it = 0; it < 4; ++it) {
        int pidx = t + 512 * it;
        int row = pidx >> 7;
        int c8 = (pidx & 127) * 8;
        int gi = i0 + row;
        float sc = (gi == 0) ? 0.f : LAMB / fmaxf(rtot[row], 1e-10f);
        float4 v0 = *(const float4*)&strip[row][c8];
        float4 v1 = *(const float4*)&strip[row][c8 + 4];
        uint4 p;
        unsigned short* pp = (unsigned short*)&p;
        pp[0] = f2bf((c8 == 0) ? 0.f : v0.x * sc);
        pp[1] = f2bf(v0.y * sc); pp[2] = f2bf(v0.z * sc); pp[3] = f2bf(v0.w * sc);
        pp[4] = f2bf(v1.x * sc); pp[5] = f2bf(v1.y * sc);
        pp[6] = f2bf(v1.z * sc); pp[7] = f2bf(v1.w * sc);
        *(uint4*)(Bb + gi * N + c8) = p;
    }
}

// ---------------- K5: v[r] = base[r] + (M z)[r], bf16 matrix ----------
__global__ __launch_bounds__(256) void k_mvb(
    const unsigned short* __restrict__ M, const float* __restrict__ base,
    const float* __restrict__ z, float* __restrict__ v)
{
    const int r = (blockIdx.x * 256 + threadIdx.x) >> 6;
    const int lane = threadIdx.x & 63;
    const uint4* m4 = (const uint4*)(M + r * N + lane * 16);
    const float4* z4 = (const float4*)(z + lane * 16);
    uint4 ma = m4[0], mb = m4[1];
    float4 z0 = z4[0], z1 = z4[1], z2 = z4[2], z3 = z4[3];
    float acc = 0.f;
    acc += bf2f((unsigned short)(ma.x)) * z0.x + bf2f((unsigned short)(ma.x >> 16)) * z0.y;
    acc += bf2f((unsigned short)(ma.y)) * z0.z + bf2f((unsigned short)(ma.y >> 16)) * z0.w;
    acc += bf2f((unsigned short)(ma.z)) * z1.x + bf2f((unsigned short)(ma.z >> 16)) * z1.y;
    acc += bf2f((unsigned short)(ma.w)) * z1.z + bf2f((unsigned short)(ma.w >> 16)) * z1.w;
    acc += bf2f((unsigned short)(mb.x)) * z2.x + bf2f((unsigned short)(mb.x >> 16)) * z2.y;
    acc += bf2f((unsigned short)(mb.y)) * z2.z + bf2f((unsigned short)(mb.y >> 16)) * z2.w;
    acc += bf2f((unsigned short)(mb.z)) * z3.x + bf2f((unsigned short)(mb.z >> 16)) * z3.y;
    acc += bf2f((unsigned short)(mb.w)) * z3.z + bf2f((unsigned short)(mb.w >> 16)) * z3.w;
    #pragma unroll
    for (int off = 32; off >= 1; off >>= 1) acc += __shfl_xor(acc, off, 64);
    if (lane == 0) v[r] = base[r] + acc;
}

// ---------------- K6: Aitken extrapolation + epilogue (one block) ----------
// u = zM + (lam/(1-lam))*(zM-zM1), lam = <d1,d2>/<d2,d2>, d1=zM-zM1, d2=zM1-zM2.
// Then P=0.1*u[1:]; center; relu*100; softmax.
__global__ __launch_bounds__(1024) void k_epilogue(
    const float* __restrict__ zM, const float* __restrict__ zM1,
    const float* __restrict__ zM2, float* __restrict__ out)
{
    __shared__ float red[16];
    __shared__ float bval;
    __shared__ float ush[1024];
    const int t = threadIdx.x;
    const int wv = t >> 6, lane = t & 63;

    const float a  = zM[t];
    const float b  = zM1[t];
    const float c  = zM2[t];
    const float d1 = a - b;
    const float d2 = b - c;

    // dot(d1,d2)
    float s = d1 * d2;
    #pragma unroll
    for (int off = 32; off >= 1; off >>= 1) s += __shfl_down(s, off, 64);
    if (lane == 0) red[wv] = s;
    __syncthreads();
    if (t < 64) {
        float s2 = (t < 16) ? red[t] : 0.f;
        #pragma unroll
        for (int off = 8; off >= 1; off >>= 1) s2 += __shfl_down(s2, off, 64);
        if (t == 0) bval = s2;
    }
    __syncthreads();
    const float dot12 = bval;
    __syncthreads();

    // dot(d2,d2)
    s = d2 * d2;
    #pragma unroll
    for (int off = 32; off >= 1; off >>= 1) s += __shfl_down(s, off, 64);
    if (lane == 0) red[wv] = s;
    __syncthreads();
    if (t < 64) {
        float s2 = (t < 16) ? red[t] : 0.f;
        #pragma unroll
        for (int off = 8; off >= 1; off >>= 1) s2 += __shfl_down(s2, off, 64);
        if (t == 0) bval = s2;
    }
    __syncthreads();
    const float dot22 = bval;
    __syncthreads();

    float lam = dot12 / fmaxf(dot22, 1e-30f);
    lam = fminf(fmaxf(lam, 0.0f), 0.95f);
    ush[t] = a + (lam / (1.0f - lam)) * d1;   // u_ext[t]
    __syncthreads();

    const bool valid = t < NM1;
    float P = valid ? 0.1f * ush[t + 1] : 0.f;

    // mean
    s = P;
    #pragma unroll
    for (int off = 32; off >= 1; off >>= 1) s += __shfl_down(s, off, 64);
    if (lane == 0) red[wv] = s;
    __syncthreads();
    if (t < 64) {
        float s2 = (t < 16) ? red[t] : 0.f;
        #pragma unroll
        for (int off = 8; off >= 1; off >>= 1) s2 += __shfl_down(s2, off, 64);
        if (t == 0) bval = s2 / 1023.0f;
    }
    __syncthreads();
    const float mean = bval;
    P = valid ? fmaxf(P - mean, 0.f) * 100.f : 0.f;

    // max
    __syncthreads();
    float m = P;
    #pragma unroll
    for (int off = 32; off >= 1; off >>= 1) m = fmaxf(m, __shfl_down(m, off, 64));
    if (lane == 0) red[wv] = m;
    __syncthreads();
    if (t < 64) {
        float m2 = (t < 16) ? red[t] : 0.f;
        #pragma unroll
        for (int off = 8; off >= 1; off >>= 1) m2 = fmaxf(m2, __shfl_down(m2, off, 64));
        if (t == 0) bval = m2;
    }
    __syncthreads();
    const float gmax = bval;
    const float e = valid ? expf(P - gmax) : 0.f;

    // sum
    __syncthreads();
    s = e;
    #pragma unroll
    for (int off = 32; off >= 1; off >>= 1) s += __shfl_down(s, off, 64);
    if (lane == 0) red[wv] = s;
    __syncthreads();
    if (t < 64) {
        float s2 = (t < 16) ? red[t] : 0.f;
        #pragma unroll
        for (int off = 8; off >= 1; off >>= 1) s2 += __shfl_down(s2, off, 64);
        if (t == 0) bval = s2;
    }
    __syncthreads();
    if (valid) out[t] = e / bval;
}

extern "C" void kernel_launch(void* const* d_in, const int* in_sizes, int n_in,
                              void* d_out, int out_size, void* d_ws, size_t ws_size,
                              hipStream_t stream) {
    const float* f  = (const float*)d_in[0];
    const float* w1 = (const float*)d_in[1];
    const float* b1 = (const float*)d_in[2];
    const float* w2 = (const float*)d_in[3];
    const float* b2 = (const float*)d_in[4];
    const float* w3 = (const float*)d_in[5];
    const float* b3 = (const float*)d_in[6];
    const float* w4 = (const float*)d_in[7];
    const float* b4 = (const float*)d_in[8];
    float* ws = (float*)d_ws;

    // Offsets in FLOAT units. bf16 1024x1024 matrix = 524288 floats of space.
    float* S     = ws;                  // 16384
    float* R     = ws + 16384;          // 16384
    float* Wboth = ws + 32768;          // 32768
    float* bboth = ws + 65536;          // 256
    float* t1v   = ws + 65792;          // 128
    float* t2v   = ws + 65920;          // 128
    float* fn2   = ws + 66048;          // 1024 (fn2/mag contiguous for zero-init)
    float* mag   = ws + 67072;          // 1024
    float* P0f   = ws + 68096;          // 1024
    float* tb0   = ws + 69120;          // 1024
    float* tb1   = ws + 70144;          // 1024
    float* tb2   = ws + 71168;          // 1024
    unsigned short* xb = (unsigned short*)(ws + 72192);   // 65536 floats
    unsigned short* Bb = (unsigned short*)(ws + 137728);  // 524288 floats
    float* out = (float*)d_out;

    k_compose_a<<<130, 256, 0, stream>>>(w1, w3, w2, w4, b2, b3, b4,
                                         S, R, t1v, t2v, fn2);
    k_compose_b<<<129, 256, 0, stream>>>(w4, S, R, t1v, t2v, b1, b4, Wboth, bboth);

    k_gemm<<<dim3(4, 16), 256, 0, stream>>>(f, Wboth, bboth, xb, fn2, mag);
    k_affB<<<64, 512, 0, stream>>>(xb, mag, fn2, Bb, P0f);

    // Neumann chain z <- P0 + B z, MITERS steps, 3-buffer rotation
    float* zb[3] = {tb0, tb1, tb2};
    float* zin = P0f;
    for (int it = 0; it < MITERS; ++it) {
        float* zout = zb[it % 3];
        k_mvb<<<256, 256, 0, stream>>>(Bb, P0f, zin, zout);
        zin = zout;
    }
    // last three iterates: zM = zb[(MITERS-1)%3], zM1 = zb[(MITERS-2)%3], zM2 = zb[(MITERS-3)%3]
    k_epilogue<<<1, 1024, 0, stream>>>(zb[(MITERS - 1) % 3],
                                       zb[(MITERS - 2) % 3],
                                       zb[(MITERS - 3) % 3], out);
}